// Round 4
// baseline (358.350 us; speedup 1.0000x reference)
//
#include <hip/hip_runtime.h>
#include <hip/hip_bf16.h>
#include <hip/hip_fp16.h>
#include <stdint.h>

typedef _Float16 half8_t __attribute__((ext_vector_type(8)));
typedef float f32x4_t __attribute__((ext_vector_type(4)));

// ---------------------------------------------------------------------------
// GCN 2-layer, fp16-MFMA path, chunk-major intermediates:
//   g = (x@W)*dis[row]  stored as [chunk][N][32] fp16 (chunk = 32 cols)
//   out[i] = dis[i]*(sum_e g[src]+g[i]) + b, aggregated per chunk with
//   chunk pinned to one XCD (blockIdx % nchunks) so gathers are L2-resident.
// ---------------------------------------------------------------------------

__global__ void detect_i64_kernel(const int* __restrict__ idx, int* __restrict__ flag) {
    int t = threadIdx.x;
    int v = idx[2 * t + 1];
    unsigned long long b = __ballot(v == 0);
    if (t == 0) *flag = (b == 0xFFFFFFFFFFFFFFFFULL) ? 1 : 0;
}

__device__ __forceinline__ int load_idx(const int* __restrict__ idx, long long pos, int is64) {
    return is64 ? idx[2 * pos] : idx[pos];
}

__global__ void count_edges_kernel(const int* __restrict__ idx, const int* __restrict__ flag,
                                   int* __restrict__ counts, int E, int N) {
    int e = blockIdx.x * blockDim.x + threadIdx.x;
    if (e >= E) return;
    int is64 = *flag;
    int d = load_idx(idx, (long long)E + e, is64);
    if ((unsigned)d < (unsigned)N) atomicAdd(&counts[d], 1);
}

__global__ __launch_bounds__(1024) void scan1_kernel(const int* __restrict__ counts,
                                                     int* __restrict__ offsets,
                                                     int* __restrict__ partials, int n) {
    __shared__ int buf[1024];
    int i = blockIdx.x * 1024 + threadIdx.x;
    int v = (i < n) ? counts[i] : 0;
    buf[threadIdx.x] = v;
    __syncthreads();
    #pragma unroll
    for (int off = 1; off < 1024; off <<= 1) {
        int t = (threadIdx.x >= (unsigned)off) ? buf[threadIdx.x - off] : 0;
        __syncthreads();
        buf[threadIdx.x] += t;
        __syncthreads();
    }
    if (i < n) offsets[i] = buf[threadIdx.x] - v;    // local exclusive
    if (threadIdx.x == 1023) partials[blockIdx.x] = buf[1023];
}

// Wave-scan of block partials (nb <= 64 expected; serial fallback otherwise).
__global__ void scan2_kernel(int* __restrict__ partials, int* __restrict__ offsets,
                             int nb, int n) {
    if (nb <= 64) {
        int t = threadIdx.x;
        int orig = (t < nb) ? partials[t] : 0;
        int v = orig;
        #pragma unroll
        for (int off = 1; off < 64; off <<= 1) {
            int u = __shfl_up(v, off);
            if (t >= off) v += u;
        }
        if (t < nb) partials[t] = v - orig;
        if (t == nb - 1) offsets[n] = v;
    } else if (threadIdx.x == 0) {
        int s = 0;
        for (int b = 0; b < nb; ++b) { int t2 = partials[b]; partials[b] = s; s += t2; }
        offsets[n] = s;
    }
}

__global__ __launch_bounds__(1024) void scan3_kernel(const int* __restrict__ counts,
                                                     int* __restrict__ offsets,
                                                     int* __restrict__ cursor,
                                                     float* __restrict__ dis,
                                                     const int* __restrict__ partials, int n) {
    int i = blockIdx.x * 1024 + threadIdx.x;
    if (i >= n) return;
    int o = offsets[i] + partials[blockIdx.x];
    offsets[i] = o;
    cursor[i] = o;
    dis[i] = rsqrtf((float)(counts[i] + 1));
}

__global__ void fill_csr_kernel(const int* __restrict__ idx, const int* __restrict__ flag,
                                int* __restrict__ cursor, int* __restrict__ csr_src,
                                int E, int N) {
    int e = blockIdx.x * blockDim.x + threadIdx.x;
    if (e >= E) return;
    int is64 = *flag;
    int s = load_idx(idx, e, is64);
    int d = load_idx(idx, (long long)E + e, is64);
    if ((unsigned)d < (unsigned)N) {
        int pos = atomicAdd(&cursor[d], 1);
        csr_src[pos] = ((unsigned)s < (unsigned)N) ? s : 0;
    }
}

// Transpose-convert W1 [512][256] -> w1t fp16 [256][512], W2 [256][64] -> w2t fp16 [64][256].
__global__ void wt_kernel(const float* __restrict__ W1, const float* __restrict__ W2,
                          _Float16* __restrict__ w1t, _Float16* __restrict__ w2t) {
    int p = blockIdx.x * 256 + threadIdx.x;
    if (p < 512 * 256) {
        int k = p >> 8, n = p & 255;
        w1t[n * 512 + k] = (_Float16)W1[p];
    } else {
        int q = p - 512 * 256;
        if (q < 256 * 64) {
            int k = q >> 6, n = q & 63;
            w2t[n * 256 + k] = (_Float16)W2[q];
        }
    }
}

// ---------------------------------------------------------------------------
// GEMM1: h1[chunk][M][32] = fp16( (x[M,512] @ W1) * dis[row] ).
// Tile 128 x 256 (full N), BK=32, 4 waves, wave-tile 64x128, MFMA 16x16x32 f16.
// ---------------------------------------------------------------------------
__global__ __launch_bounds__(256, 1) void gemm1_kernel(
        const float* __restrict__ x, const _Float16* __restrict__ w1t,
        const float* __restrict__ dis, _Float16* __restrict__ h1s, int M) {
    __shared__ _Float16 As[4 * 128 * 8];
    __shared__ _Float16 Bs[4 * 256 * 8];
    const int tid = threadIdx.x;
    const int brow = blockIdx.x * 128;
    const int w = tid >> 6, lane = tid & 63;
    const int wr = w >> 1, wc = w & 1;
    const int lrow = lane & 15, lkb = lane >> 4;

    f32x4_t acc[4][8];
    #pragma unroll
    for (int mi = 0; mi < 4; ++mi)
        #pragma unroll
        for (int nj = 0; nj < 8; ++nj) acc[mi][nj] = (f32x4_t)0.f;

    for (int k0 = 0; k0 < 512; k0 += 32) {
        #pragma unroll
        for (int i = 0; i < 2; ++i) {
            int p = tid + i * 256;
            int row = p >> 2, kb = p & 3;
            int gr = brow + row;
            float4 u = make_float4(0.f, 0.f, 0.f, 0.f);
            float4 v = make_float4(0.f, 0.f, 0.f, 0.f);
            if (gr < M) {
                const float* src = &x[(size_t)gr * 512 + k0 + kb * 8];
                u = *(const float4*)src;
                v = *(const float4*)(src + 4);
            }
            half8_t h;
            h[0] = (_Float16)u.x; h[1] = (_Float16)u.y;
            h[2] = (_Float16)u.z; h[3] = (_Float16)u.w;
            h[4] = (_Float16)v.x; h[5] = (_Float16)v.y;
            h[6] = (_Float16)v.z; h[7] = (_Float16)v.w;
            *(half8_t*)&As[((kb << 7) + row) << 3] = h;
        }
        #pragma unroll
        for (int i = 0; i < 4; ++i) {
            int p = tid + i * 256;
            int n = p >> 2, kb = p & 3;
            half8_t h = *(const half8_t*)&w1t[(size_t)n * 512 + k0 + kb * 8];
            *(half8_t*)&Bs[((kb << 8) + n) << 3] = h;
        }
        __syncthreads();
        half8_t a[4], b[8];
        #pragma unroll
        for (int mi = 0; mi < 4; ++mi)
            a[mi] = *(const half8_t*)&As[((lkb << 7) + wr * 64 + mi * 16 + lrow) << 3];
        #pragma unroll
        for (int nj = 0; nj < 8; ++nj)
            b[nj] = *(const half8_t*)&Bs[((lkb << 8) + wc * 128 + nj * 16 + lrow) << 3];
        #pragma unroll
        for (int mi = 0; mi < 4; ++mi)
            #pragma unroll
            for (int nj = 0; nj < 8; ++nj)
                acc[mi][nj] = __builtin_amdgcn_mfma_f32_16x16x32_f16(a[mi], b[nj], acc[mi][nj], 0, 0, 0);
        __syncthreads();
    }
    // Epilogue: C/D layout col=lane&15, row=(lane>>4)*4+r. Chunk-major store.
    #pragma unroll
    for (int mi = 0; mi < 4; ++mi) {
        #pragma unroll
        for (int r = 0; r < 4; ++r) {
            int grow = brow + wr * 64 + mi * 16 + (lane >> 4) * 4 + r;
            if (grow >= M) continue;
            float s = dis[grow];
            #pragma unroll
            for (int nj = 0; nj < 8; ++nj) {
                int col = wc * 128 + nj * 16 + lrow;
                h1s[((size_t)(col >> 5) * M + grow) * 32 + (col & 31)] =
                    (_Float16)(acc[mi][nj][r] * s);
            }
        }
    }
}

// ---------------------------------------------------------------------------
// GEMM2: h2[chunk][M][32] = fp16( (a1 @ W2) * dis[row] ), a1 chunk-major.
// Tile 64x64, 4 waves, wave = 16 rows x 64 cols. K=256.
// ---------------------------------------------------------------------------
__global__ __launch_bounds__(256) void gemm2_kernel(
        const _Float16* __restrict__ a1s, const _Float16* __restrict__ w2t,
        const float* __restrict__ dis, _Float16* __restrict__ h2s, int M) {
    __shared__ _Float16 As[4 * 64 * 8];
    __shared__ _Float16 Bs[4 * 64 * 8];
    const int tid = threadIdx.x;
    const int brow = blockIdx.x * 64;
    const int w = tid >> 6, lane = tid & 63;
    const int lrow = lane & 15, lkb = lane >> 4;

    f32x4_t acc[4];
    #pragma unroll
    for (int nj = 0; nj < 4; ++nj) acc[nj] = (f32x4_t)0.f;

    for (int k0 = 0; k0 < 256; k0 += 32) {
        {   // Stage A from chunk-major a1: chunk = k0>>5, 16B contiguous pieces.
            int row = tid >> 2, kb = tid & 3;
            int gr = brow + row;
            half8_t h = (half8_t)(_Float16)0.f;
            if (gr < M) h = *(const half8_t*)&a1s[((size_t)(k0 >> 5) * M + gr) * 32 + kb * 8];
            *(half8_t*)&As[((kb << 6) + row) << 3] = h;
            int n = row;
            half8_t hb = *(const half8_t*)&w2t[(size_t)n * 256 + k0 + kb * 8];
            *(half8_t*)&Bs[((kb << 6) + n) << 3] = hb;
        }
        __syncthreads();
        half8_t a = *(const half8_t*)&As[((lkb << 6) + w * 16 + lrow) << 3];
        half8_t b[4];
        #pragma unroll
        for (int nj = 0; nj < 4; ++nj)
            b[nj] = *(const half8_t*)&Bs[((lkb << 6) + nj * 16 + lrow) << 3];
        #pragma unroll
        for (int nj = 0; nj < 4; ++nj)
            acc[nj] = __builtin_amdgcn_mfma_f32_16x16x32_f16(a, b[nj], acc[nj], 0, 0, 0);
        __syncthreads();
    }
    #pragma unroll
    for (int r = 0; r < 4; ++r) {
        int grow = brow + w * 16 + (lane >> 4) * 4 + r;
        if (grow >= M) continue;
        float s = dis[grow];
        #pragma unroll
        for (int nj = 0; nj < 4; ++nj) {
            int col = nj * 16 + lrow;
            h2s[((size_t)(col >> 5) * M + grow) * 32 + (col & 31)] =
                (_Float16)(acc[nj][r] * s);
        }
    }
}

__device__ __forceinline__ float4 up4(uint2 v) {
    __half2 h0 = *reinterpret_cast<__half2*>(&v.x);
    __half2 h1 = *reinterpret_cast<__half2*>(&v.y);
    float2 a = __half22float2(h0), b = __half22float2(h1);
    return make_float4(a.x, a.y, b.x, b.y);
}

// ---------------------------------------------------------------------------
// Chunked aggregation over [NCH][N][32] fp16. chunk = blockIdx % NCH pins each
// chunk to one XCD (round-robin dispatch) -> 3.2MB working set, L2-resident.
// Block = 4 waves = 4 nodes; wave = 8 edge-slots x 8 lanes x 4 fp16.
// FP16OUT=1: out = relu(...) -> fp16 chunk-major. FP16OUT=0: out f32 [N][NCH*32].
// ---------------------------------------------------------------------------
template<int NCH, int FP16OUT>
__global__ __launch_bounds__(256) void aggc_kernel(
        const _Float16* __restrict__ g, const int* __restrict__ offsets,
        const int* __restrict__ csr_src, const float* __restrict__ dis,
        const float* __restrict__ bias, void* __restrict__ out, int N) {
    const int chunk = blockIdx.x % NCH;
    const int node = (blockIdx.x / NCH) * 4 + (threadIdx.x >> 6);
    if (node >= N) return;
    const int lane = threadIdx.x & 63;
    const int slot = lane >> 3, cl = lane & 7;
    const uint2* gc = (const uint2*)g + (size_t)chunk * N * 8;   // row = 8 uint2

    float4 acc = make_float4(0.f, 0.f, 0.f, 0.f);
    const int s0 = offsets[node], s1 = offsets[node + 1];
    for (int e = s0 + slot; e < s1; e += 8) {
        int s = csr_src[e];
        float4 v = up4(gc[(size_t)s * 8 + cl]);
        acc.x += v.x; acc.y += v.y; acc.z += v.z; acc.w += v.w;
    }
    if (slot == 0) {
        float4 v = up4(gc[(size_t)node * 8 + cl]);
        acc.x += v.x; acc.y += v.y; acc.z += v.z; acc.w += v.w;
    }
    #pragma unroll
    for (int m = 8; m <= 32; m <<= 1) {
        acc.x += __shfl_xor(acc.x, m);
        acc.y += __shfl_xor(acc.y, m);
        acc.z += __shfl_xor(acc.z, m);
        acc.w += __shfl_xor(acc.w, m);
    }
    if (slot == 0) {
        float s = dis[node];
        float4 bb = *(const float4*)&bias[chunk * 32 + cl * 4];
        float4 o;
        o.x = fmaf(s, acc.x, bb.x);
        o.y = fmaf(s, acc.y, bb.y);
        o.z = fmaf(s, acc.z, bb.z);
        o.w = fmaf(s, acc.w, bb.w);
        if (FP16OUT) {
            o.x = fmaxf(o.x, 0.f); o.y = fmaxf(o.y, 0.f);
            o.z = fmaxf(o.z, 0.f); o.w = fmaxf(o.w, 0.f);
            __half2 p0 = __float22half2_rn(make_float2(o.x, o.y));
            __half2 p1 = __float22half2_rn(make_float2(o.z, o.w));
            uint2 pv;
            pv.x = *reinterpret_cast<unsigned*>(&p0);
            pv.y = *reinterpret_cast<unsigned*>(&p1);
            ((uint2*)out)[((size_t)chunk * N + node) * 8 + cl] = pv;
        } else {
            ((float4*)out)[(size_t)node * (NCH * 8) + chunk * 8 + cl] = o;
        }
    }
}

extern "C" void kernel_launch(void* const* d_in, const int* in_sizes, int n_in,
                              void* d_out, int out_size, void* d_ws, size_t ws_size,
                              hipStream_t stream) {
    const float* x  = (const float*)d_in[0];
    const float* W1 = (const float*)d_in[1];
    const float* b1 = (const float*)d_in[2];
    const float* W2 = (const float*)d_in[3];
    const float* b2 = (const float*)d_in[4];
    const int* eidx = (const int*)d_in[5];

    const int HID = in_sizes[2];            // 256
    const int OUT = in_sizes[4];            // 64
    const int IN  = in_sizes[1] / HID;      // 512
    const int N   = in_sizes[0] / IN;       // 50000
    const int E   = in_sizes[5] / 2;        // 800000

    char* ws = (char*)d_ws;
    size_t off = 0;
    auto alloc = [&](size_t bytes) {
        off = (off + 255) & ~(size_t)255;
        char* p = ws + off;
        off += bytes;
        return p;
    };
    float* dis     = (float*)alloc((size_t)N * 4);
    int* counts    = (int*)alloc((size_t)N * 4);
    int* offsets   = (int*)alloc((size_t)(N + 1) * 4);
    int* cursor    = (int*)alloc((size_t)N * 4);
    int* partials  = (int*)alloc(4096);
    int* flag      = (int*)alloc(256);
    int* csr_src   = (int*)alloc((size_t)E * 4);
    _Float16* w1t  = (_Float16*)alloc((size_t)IN * HID * 2);
    _Float16* w2t  = (_Float16*)alloc((size_t)HID * OUT * 2);
    _Float16* h1s  = (_Float16*)alloc((size_t)N * HID * 2);   // [8][N][32]
    _Float16* a1s  = (_Float16*)alloc((size_t)N * HID * 2);   // [8][N][32]
    _Float16* h2s  = (_Float16*)alloc((size_t)N * OUT * 2);   // [2][N][32]

    const int nb = (N + 1023) / 1024;

    hipMemsetAsync(counts, 0, (size_t)N * 4, stream);
    detect_i64_kernel<<<1, 64, 0, stream>>>(eidx, flag);
    count_edges_kernel<<<(E + 255) / 256, 256, 0, stream>>>(eidx, flag, counts, E, N);
    scan1_kernel<<<nb, 1024, 0, stream>>>(counts, offsets, partials, N);
    scan2_kernel<<<1, 64, 0, stream>>>(partials, offsets, nb, N);
    scan3_kernel<<<nb, 1024, 0, stream>>>(counts, offsets, cursor, dis, partials, N);
    fill_csr_kernel<<<(E + 255) / 256, 256, 0, stream>>>(eidx, flag, cursor, csr_src, E, N);
    wt_kernel<<<(IN * HID + HID * OUT + 255) / 256, 256, 0, stream>>>(W1, W2, w1t, w2t);

    // Layer 1
    gemm1_kernel<<<(N + 127) / 128, 256, 0, stream>>>(x, w1t, dis, h1s, N);
    aggc_kernel<8, 1><<<((N + 3) / 4) * 8, 256, 0, stream>>>(h1s, offsets, csr_src, dis,
                                                             b1, a1s, N);
    // Layer 2
    gemm2_kernel<<<(N + 63) / 64, 256, 0, stream>>>(a1s, w2t, dis, h2s, N);
    aggc_kernel<2, 0><<<((N + 3) / 4) * 2, 256, 0, stream>>>(h2s, offsets, csr_src, dis,
                                                             b2, d_out, N);
}

// Round 5
// 274.812 us; speedup vs baseline: 1.3040x; 1.3040x over previous
//
#include <hip/hip_runtime.h>
#include <hip/hip_bf16.h>
#include <hip/hip_fp16.h>
#include <stdint.h>

typedef _Float16 half8_t __attribute__((ext_vector_type(8)));
typedef float f32x4_t __attribute__((ext_vector_type(4)));

// ---------------------------------------------------------------------------
// GCN 2-layer, fp16-MFMA path, chunk-major intermediates:
//   g = (x@W)*dis[row]  stored as [chunk][N][32] fp16 (chunk = 32 cols)
//   out[i] = dis[i]*(sum_e g[src]+g[i]) + b, aggregated per chunk with
//   chunk pinned to one XCD (blockIdx % nchunks) so gathers are L2-resident.
//   Aggregation: one node per 8-lane group, register accumulate, no reduce.
// ---------------------------------------------------------------------------

__global__ void detect_i64_kernel(const int* __restrict__ idx, int* __restrict__ flag) {
    int t = threadIdx.x;
    int v = idx[2 * t + 1];
    unsigned long long b = __ballot(v == 0);
    if (t == 0) *flag = (b == 0xFFFFFFFFFFFFFFFFULL) ? 1 : 0;
}

__device__ __forceinline__ int load_idx(const int* __restrict__ idx, long long pos, int is64) {
    return is64 ? idx[2 * pos] : idx[pos];
}

__global__ void count_edges_kernel(const int* __restrict__ idx, const int* __restrict__ flag,
                                   int* __restrict__ counts, int E, int N) {
    int e = blockIdx.x * blockDim.x + threadIdx.x;
    if (e >= E) return;
    int is64 = *flag;
    int d = load_idx(idx, (long long)E + e, is64);
    if ((unsigned)d < (unsigned)N) atomicAdd(&counts[d], 1);
}

__global__ __launch_bounds__(1024) void scan1_kernel(const int* __restrict__ counts,
                                                     int* __restrict__ offsets,
                                                     int* __restrict__ partials, int n) {
    __shared__ int buf[1024];
    int i = blockIdx.x * 1024 + threadIdx.x;
    int v = (i < n) ? counts[i] : 0;
    buf[threadIdx.x] = v;
    __syncthreads();
    #pragma unroll
    for (int off = 1; off < 1024; off <<= 1) {
        int t = (threadIdx.x >= (unsigned)off) ? buf[threadIdx.x - off] : 0;
        __syncthreads();
        buf[threadIdx.x] += t;
        __syncthreads();
    }
    if (i < n) offsets[i] = buf[threadIdx.x] - v;    // local exclusive
    if (threadIdx.x == 1023) partials[blockIdx.x] = buf[1023];
}

// Wave-scan of block partials (nb <= 64 expected; serial fallback otherwise).
__global__ void scan2_kernel(int* __restrict__ partials, int* __restrict__ offsets,
                             int nb, int n) {
    if (nb <= 64) {
        int t = threadIdx.x;
        int orig = (t < nb) ? partials[t] : 0;
        int v = orig;
        #pragma unroll
        for (int off = 1; off < 64; off <<= 1) {
            int u = __shfl_up(v, off);
            if (t >= off) v += u;
        }
        if (t < nb) partials[t] = v - orig;
        if (t == nb - 1) offsets[n] = v;
    } else if (threadIdx.x == 0) {
        int s = 0;
        for (int b = 0; b < nb; ++b) { int t2 = partials[b]; partials[b] = s; s += t2; }
        offsets[n] = s;
    }
}

__global__ __launch_bounds__(1024) void scan3_kernel(const int* __restrict__ counts,
                                                     int* __restrict__ offsets,
                                                     int* __restrict__ cursor,
                                                     float* __restrict__ dis,
                                                     const int* __restrict__ partials, int n) {
    int i = blockIdx.x * 1024 + threadIdx.x;
    if (i >= n) return;
    int o = offsets[i] + partials[blockIdx.x];
    offsets[i] = o;
    cursor[i] = o;
    dis[i] = rsqrtf((float)(counts[i] + 1));
}

__global__ void fill_csr_kernel(const int* __restrict__ idx, const int* __restrict__ flag,
                                int* __restrict__ cursor, int* __restrict__ csr_src,
                                int E, int N) {
    int e = blockIdx.x * blockDim.x + threadIdx.x;
    if (e >= E) return;
    int is64 = *flag;
    int s = load_idx(idx, e, is64);
    int d = load_idx(idx, (long long)E + e, is64);
    if ((unsigned)d < (unsigned)N) {
        int pos = atomicAdd(&cursor[d], 1);
        csr_src[pos] = ((unsigned)s < (unsigned)N) ? s : 0;
    }
}

// Transpose-convert W1 [512][256] -> w1t fp16 [256][512], W2 [256][64] -> w2t fp16 [64][256].
__global__ void wt_kernel(const float* __restrict__ W1, const float* __restrict__ W2,
                          _Float16* __restrict__ w1t, _Float16* __restrict__ w2t) {
    int p = blockIdx.x * 256 + threadIdx.x;
    if (p < 512 * 256) {
        int k = p >> 8, n = p & 255;
        w1t[n * 512 + k] = (_Float16)W1[p];
    } else {
        int q = p - 512 * 256;
        if (q < 256 * 64) {
            int k = q >> 6, n = q & 63;
            w2t[n * 256 + k] = (_Float16)W2[q];
        }
    }
}

// ---------------------------------------------------------------------------
// GEMM1: h1[chunk][M][32] = fp16( (x[M,512] @ W1) * dis[row] ).
// Tile 128 x 256 (full N), BK=32, 4 waves, wave-tile 64x128, MFMA 16x16x32 f16.
// ---------------------------------------------------------------------------
__global__ __launch_bounds__(256, 1) void gemm1_kernel(
        const float* __restrict__ x, const _Float16* __restrict__ w1t,
        const float* __restrict__ dis, _Float16* __restrict__ h1s, int M) {
    __shared__ _Float16 As[4 * 128 * 8];
    __shared__ _Float16 Bs[4 * 256 * 8];
    const int tid = threadIdx.x;
    const int brow = blockIdx.x * 128;
    const int w = tid >> 6, lane = tid & 63;
    const int wr = w >> 1, wc = w & 1;
    const int lrow = lane & 15, lkb = lane >> 4;

    f32x4_t acc[4][8];
    #pragma unroll
    for (int mi = 0; mi < 4; ++mi)
        #pragma unroll
        for (int nj = 0; nj < 8; ++nj) acc[mi][nj] = (f32x4_t)0.f;

    for (int k0 = 0; k0 < 512; k0 += 32) {
        #pragma unroll
        for (int i = 0; i < 2; ++i) {
            int p = tid + i * 256;
            int row = p >> 2, kb = p & 3;
            int gr = brow + row;
            float4 u = make_float4(0.f, 0.f, 0.f, 0.f);
            float4 v = make_float4(0.f, 0.f, 0.f, 0.f);
            if (gr < M) {
                const float* src = &x[(size_t)gr * 512 + k0 + kb * 8];
                u = *(const float4*)src;
                v = *(const float4*)(src + 4);
            }
            half8_t h;
            h[0] = (_Float16)u.x; h[1] = (_Float16)u.y;
            h[2] = (_Float16)u.z; h[3] = (_Float16)u.w;
            h[4] = (_Float16)v.x; h[5] = (_Float16)v.y;
            h[6] = (_Float16)v.z; h[7] = (_Float16)v.w;
            *(half8_t*)&As[((kb << 7) + row) << 3] = h;
        }
        #pragma unroll
        for (int i = 0; i < 4; ++i) {
            int p = tid + i * 256;
            int n = p >> 2, kb = p & 3;
            half8_t h = *(const half8_t*)&w1t[(size_t)n * 512 + k0 + kb * 8];
            *(half8_t*)&Bs[((kb << 8) + n) << 3] = h;
        }
        __syncthreads();
        half8_t a[4], b[8];
        #pragma unroll
        for (int mi = 0; mi < 4; ++mi)
            a[mi] = *(const half8_t*)&As[((lkb << 7) + wr * 64 + mi * 16 + lrow) << 3];
        #pragma unroll
        for (int nj = 0; nj < 8; ++nj)
            b[nj] = *(const half8_t*)&Bs[((lkb << 8) + wc * 128 + nj * 16 + lrow) << 3];
        #pragma unroll
        for (int mi = 0; mi < 4; ++mi)
            #pragma unroll
            for (int nj = 0; nj < 8; ++nj)
                acc[mi][nj] = __builtin_amdgcn_mfma_f32_16x16x32_f16(a[mi], b[nj], acc[mi][nj], 0, 0, 0);
        __syncthreads();
    }
    // Epilogue: C/D layout col=lane&15, row=(lane>>4)*4+r. Chunk-major store.
    #pragma unroll
    for (int mi = 0; mi < 4; ++mi) {
        #pragma unroll
        for (int r = 0; r < 4; ++r) {
            int grow = brow + wr * 64 + mi * 16 + (lane >> 4) * 4 + r;
            if (grow >= M) continue;
            float s = dis[grow];
            #pragma unroll
            for (int nj = 0; nj < 8; ++nj) {
                int col = wc * 128 + nj * 16 + lrow;
                h1s[((size_t)(col >> 5) * M + grow) * 32 + (col & 31)] =
                    (_Float16)(acc[mi][nj][r] * s);
            }
        }
    }
}

// ---------------------------------------------------------------------------
// GEMM2: h2[chunk][M][32] = fp16( (a1 @ W2) * dis[row] ), a1 chunk-major.
// Tile 64x64, 4 waves, wave = 16 rows x 64 cols. K=256.
// ---------------------------------------------------------------------------
__global__ __launch_bounds__(256) void gemm2_kernel(
        const _Float16* __restrict__ a1s, const _Float16* __restrict__ w2t,
        const float* __restrict__ dis, _Float16* __restrict__ h2s, int M) {
    __shared__ _Float16 As[4 * 64 * 8];
    __shared__ _Float16 Bs[4 * 64 * 8];
    const int tid = threadIdx.x;
    const int brow = blockIdx.x * 64;
    const int w = tid >> 6, lane = tid & 63;
    const int lrow = lane & 15, lkb = lane >> 4;

    f32x4_t acc[4];
    #pragma unroll
    for (int nj = 0; nj < 4; ++nj) acc[nj] = (f32x4_t)0.f;

    for (int k0 = 0; k0 < 256; k0 += 32) {
        {   // Stage A from chunk-major a1: chunk = k0>>5, 16B contiguous pieces.
            int row = tid >> 2, kb = tid & 3;
            int gr = brow + row;
            half8_t h = (half8_t)(_Float16)0.f;
            if (gr < M) h = *(const half8_t*)&a1s[((size_t)(k0 >> 5) * M + gr) * 32 + kb * 8];
            *(half8_t*)&As[((kb << 6) + row) << 3] = h;
            int n = row;
            half8_t hb = *(const half8_t*)&w2t[(size_t)n * 256 + k0 + kb * 8];
            *(half8_t*)&Bs[((kb << 6) + n) << 3] = hb;
        }
        __syncthreads();
        half8_t a = *(const half8_t*)&As[((lkb << 6) + w * 16 + lrow) << 3];
        half8_t b[4];
        #pragma unroll
        for (int nj = 0; nj < 4; ++nj)
            b[nj] = *(const half8_t*)&Bs[((lkb << 6) + nj * 16 + lrow) << 3];
        #pragma unroll
        for (int nj = 0; nj < 4; ++nj)
            acc[nj] = __builtin_amdgcn_mfma_f32_16x16x32_f16(a, b[nj], acc[nj], 0, 0, 0);
        __syncthreads();
    }
    #pragma unroll
    for (int r = 0; r < 4; ++r) {
        int grow = brow + w * 16 + (lane >> 4) * 4 + r;
        if (grow >= M) continue;
        float s = dis[grow];
        #pragma unroll
        for (int nj = 0; nj < 4; ++nj) {
            int col = nj * 16 + lrow;
            h2s[((size_t)(col >> 5) * M + grow) * 32 + (col & 31)] =
                (_Float16)(acc[nj][r] * s);
        }
    }
}

__device__ __forceinline__ float4 up4(uint2 v) {
    __half2 h0 = *reinterpret_cast<__half2*>(&v.x);
    __half2 h1 = *reinterpret_cast<__half2*>(&v.y);
    float2 a = __half22float2(h0), b = __half22float2(h1);
    return make_float4(a.x, a.y, b.x, b.y);
}

// ---------------------------------------------------------------------------
// Chunked aggregation over [NCH][N][32] fp16. chunk = blockIdx % NCH pins each
// chunk to one XCD (round-robin dispatch) -> 3.2MB working set, L2-resident.
// One node per 8-lane group (lane = 4 fp16 cols as uint2); each group loops
// its node's full edge list with dual accumulators; NO cross-lane reduce.
// Block = 256 thr = 32 nodes. FP16OUT=1: relu -> fp16 chunk-major.
// FP16OUT=0: f32 row-major [N][NCH*32].
// ---------------------------------------------------------------------------
template<int NCH, int FP16OUT>
__global__ __launch_bounds__(256) void aggv_kernel(
        const _Float16* __restrict__ g, const int* __restrict__ offsets,
        const int* __restrict__ csr_src, const float* __restrict__ dis,
        const float* __restrict__ bias, void* __restrict__ out, int N) {
    const int chunk = blockIdx.x % NCH;
    const int node = (blockIdx.x / NCH) * 32 + (threadIdx.x >> 3);
    if (node >= N) return;
    const int cl = threadIdx.x & 7;
    const uint2* gc = (const uint2*)g + (size_t)chunk * N * 8;   // row = 8 uint2

    const int s0 = offsets[node], s1 = offsets[node + 1];
    const float s = dis[node];
    const float4 bb = *(const float4*)&bias[chunk * 32 + cl * 4];

    // accA starts with the self-loop row.
    float4 accA = up4(gc[(size_t)node * 8 + cl]);
    float4 accB = make_float4(0.f, 0.f, 0.f, 0.f);
    int e = s0;
    for (; e + 2 <= s1; e += 2) {
        int sa = csr_src[e];
        int sb = csr_src[e + 1];
        float4 va = up4(gc[(size_t)sa * 8 + cl]);
        float4 vb = up4(gc[(size_t)sb * 8 + cl]);
        accA.x += va.x; accA.y += va.y; accA.z += va.z; accA.w += va.w;
        accB.x += vb.x; accB.y += vb.y; accB.z += vb.z; accB.w += vb.w;
    }
    if (e < s1) {
        int sa = csr_src[e];
        float4 va = up4(gc[(size_t)sa * 8 + cl]);
        accA.x += va.x; accA.y += va.y; accA.z += va.z; accA.w += va.w;
    }
    float4 o;
    o.x = fmaf(s, accA.x + accB.x, bb.x);
    o.y = fmaf(s, accA.y + accB.y, bb.y);
    o.z = fmaf(s, accA.z + accB.z, bb.z);
    o.w = fmaf(s, accA.w + accB.w, bb.w);
    if (FP16OUT) {
        o.x = fmaxf(o.x, 0.f); o.y = fmaxf(o.y, 0.f);
        o.z = fmaxf(o.z, 0.f); o.w = fmaxf(o.w, 0.f);
        __half2 p0 = __float22half2_rn(make_float2(o.x, o.y));
        __half2 p1 = __float22half2_rn(make_float2(o.z, o.w));
        uint2 pv;
        pv.x = *reinterpret_cast<unsigned*>(&p0);
        pv.y = *reinterpret_cast<unsigned*>(&p1);
        ((uint2*)out)[((size_t)chunk * N + node) * 8 + cl] = pv;
    } else {
        ((float4*)out)[(size_t)node * (NCH * 8) + chunk * 8 + cl] = o;
    }
}

extern "C" void kernel_launch(void* const* d_in, const int* in_sizes, int n_in,
                              void* d_out, int out_size, void* d_ws, size_t ws_size,
                              hipStream_t stream) {
    const float* x  = (const float*)d_in[0];
    const float* W1 = (const float*)d_in[1];
    const float* b1 = (const float*)d_in[2];
    const float* W2 = (const float*)d_in[3];
    const float* b2 = (const float*)d_in[4];
    const int* eidx = (const int*)d_in[5];

    const int HID = in_sizes[2];            // 256
    const int OUT = in_sizes[4];            // 64
    const int IN  = in_sizes[1] / HID;      // 512
    const int N   = in_sizes[0] / IN;       // 50000
    const int E   = in_sizes[5] / 2;        // 800000

    char* ws = (char*)d_ws;
    size_t off = 0;
    auto alloc = [&](size_t bytes) {
        off = (off + 255) & ~(size_t)255;
        char* p = ws + off;
        off += bytes;
        return p;
    };
    float* dis     = (float*)alloc((size_t)N * 4);
    int* counts    = (int*)alloc((size_t)N * 4);
    int* offsets   = (int*)alloc((size_t)(N + 1) * 4);
    int* cursor    = (int*)alloc((size_t)N * 4);
    int* partials  = (int*)alloc(4096);
    int* flag      = (int*)alloc(256);
    int* csr_src   = (int*)alloc((size_t)E * 4);
    _Float16* w1t  = (_Float16*)alloc((size_t)IN * HID * 2);
    _Float16* w2t  = (_Float16*)alloc((size_t)HID * OUT * 2);
    _Float16* h1s  = (_Float16*)alloc((size_t)N * HID * 2);   // [8][N][32]
    _Float16* a1s  = (_Float16*)alloc((size_t)N * HID * 2);   // [8][N][32]
    _Float16* h2s  = (_Float16*)alloc((size_t)N * OUT * 2);   // [2][N][32]

    const int nb = (N + 1023) / 1024;

    hipMemsetAsync(counts, 0, (size_t)N * 4, stream);
    detect_i64_kernel<<<1, 64, 0, stream>>>(eidx, flag);
    count_edges_kernel<<<(E + 255) / 256, 256, 0, stream>>>(eidx, flag, counts, E, N);
    scan1_kernel<<<nb, 1024, 0, stream>>>(counts, offsets, partials, N);
    scan2_kernel<<<1, 64, 0, stream>>>(partials, offsets, nb, N);
    scan3_kernel<<<nb, 1024, 0, stream>>>(counts, offsets, cursor, dis, partials, N);
    fill_csr_kernel<<<(E + 255) / 256, 256, 0, stream>>>(eidx, flag, cursor, csr_src, E, N);
    wt_kernel<<<(IN * HID + HID * OUT + 255) / 256, 256, 0, stream>>>(W1, W2, w1t, w2t);

    // Layer 1
    gemm1_kernel<<<(N + 127) / 128, 256, 0, stream>>>(x, w1t, dis, h1s, N);
    aggv_kernel<8, 1><<<((N + 31) / 32) * 8, 256, 0, stream>>>(h1s, offsets, csr_src, dis,
                                                               b1, a1s, N);
    // Layer 2
    gemm2_kernel<<<(N + 63) / 64, 256, 0, stream>>>(a1s, w2t, dis, h2s, N);
    aggv_kernel<2, 0><<<((N + 31) / 32) * 2, 256, 0, stream>>>(h2s, offsets, csr_src, dis,
                                                               b2, d_out, N);
}

// Round 6
// 244.090 us; speedup vs baseline: 1.4681x; 1.1259x over previous
//
#include <hip/hip_runtime.h>
#include <hip/hip_bf16.h>
#include <hip/hip_fp16.h>
#include <stdint.h>

typedef _Float16 half8_t __attribute__((ext_vector_type(8)));
typedef float f32x4_t __attribute__((ext_vector_type(4)));

// ---------------------------------------------------------------------------
// GCN 2-layer, fp16-MFMA path, chunk-major intermediates:
//   g = (x@W)*dis[row]  stored as [chunk][N][32] fp16 (chunk = 32 cols)
//   out[i] = dis[i]*(sum_e g[src]+g[i]) + b; aggregation chunk-pinned to XCD.
//   GEMMs: 64-row tiles (782 blocks), T14 reg-prefetch, bank-derotated LDS.
// ---------------------------------------------------------------------------

__global__ void detect_i64_kernel(const int* __restrict__ idx, int* __restrict__ flag) {
    int t = threadIdx.x;
    int v = idx[2 * t + 1];
    unsigned long long b = __ballot(v == 0);
    if (t == 0) *flag = (b == 0xFFFFFFFFFFFFFFFFULL) ? 1 : 0;
}

__device__ __forceinline__ int load_idx(const int* __restrict__ idx, long long pos, int is64) {
    return is64 ? idx[2 * pos] : idx[pos];
}

__global__ void count_edges_kernel(const int* __restrict__ idx, const int* __restrict__ flag,
                                   int* __restrict__ counts, int E, int N) {
    int e = blockIdx.x * blockDim.x + threadIdx.x;
    if (e >= E) return;
    int is64 = *flag;
    int d = load_idx(idx, (long long)E + e, is64);
    if ((unsigned)d < (unsigned)N) atomicAdd(&counts[d], 1);
}

__global__ __launch_bounds__(1024) void scan1_kernel(const int* __restrict__ counts,
                                                     int* __restrict__ offsets,
                                                     int* __restrict__ partials, int n) {
    __shared__ int buf[1024];
    int i = blockIdx.x * 1024 + threadIdx.x;
    int v = (i < n) ? counts[i] : 0;
    buf[threadIdx.x] = v;
    __syncthreads();
    #pragma unroll
    for (int off = 1; off < 1024; off <<= 1) {
        int t = (threadIdx.x >= (unsigned)off) ? buf[threadIdx.x - off] : 0;
        __syncthreads();
        buf[threadIdx.x] += t;
        __syncthreads();
    }
    if (i < n) offsets[i] = buf[threadIdx.x] - v;    // local exclusive
    if (threadIdx.x == 1023) partials[blockIdx.x] = buf[1023];
}

__global__ void scan2_kernel(int* __restrict__ partials, int* __restrict__ offsets,
                             int nb, int n) {
    if (nb <= 64) {
        int t = threadIdx.x;
        int orig = (t < nb) ? partials[t] : 0;
        int v = orig;
        #pragma unroll
        for (int off = 1; off < 64; off <<= 1) {
            int u = __shfl_up(v, off);
            if (t >= off) v += u;
        }
        if (t < nb) partials[t] = v - orig;
        if (t == nb - 1) offsets[n] = v;
    } else if (threadIdx.x == 0) {
        int s = 0;
        for (int b = 0; b < nb; ++b) { int t2 = partials[b]; partials[b] = s; s += t2; }
        offsets[n] = s;
    }
}

__global__ __launch_bounds__(1024) void scan3_kernel(const int* __restrict__ counts,
                                                     int* __restrict__ offsets,
                                                     int* __restrict__ cursor,
                                                     float* __restrict__ dis,
                                                     const int* __restrict__ partials, int n) {
    int i = blockIdx.x * 1024 + threadIdx.x;
    if (i >= n) return;
    int o = offsets[i] + partials[blockIdx.x];
    offsets[i] = o;
    cursor[i] = o;
    dis[i] = rsqrtf((float)(counts[i] + 1));
}

__global__ void fill_csr_kernel(const int* __restrict__ idx, const int* __restrict__ flag,
                                int* __restrict__ cursor, int* __restrict__ csr_src,
                                int E, int N) {
    int e = blockIdx.x * blockDim.x + threadIdx.x;
    if (e >= E) return;
    int is64 = *flag;
    int s = load_idx(idx, e, is64);
    int d = load_idx(idx, (long long)E + e, is64);
    if ((unsigned)d < (unsigned)N) {
        int pos = atomicAdd(&cursor[d], 1);
        csr_src[pos] = ((unsigned)s < (unsigned)N) ? s : 0;
    }
}

// Transpose-convert W1 [512][256] -> w1t fp16 [256][512], W2 [256][64] -> w2t fp16 [64][256].
__global__ void wt_kernel(const float* __restrict__ W1, const float* __restrict__ W2,
                          _Float16* __restrict__ w1t, _Float16* __restrict__ w2t) {
    int p = blockIdx.x * 256 + threadIdx.x;
    if (p < 512 * 256) {
        int k = p >> 8, n = p & 255;
        w1t[n * 512 + k] = (_Float16)W1[p];
    } else {
        int q = p - 512 * 256;
        if (q < 256 * 64) {
            int k = q >> 6, n = q & 63;
            w2t[n * 256 + k] = (_Float16)W2[q];
        }
    }
}

// ---------------------------------------------------------------------------
// GEMM1: h1[chunk][M][32] = fp16( (x[M,512] @ W1) * dis[row] ).
// Tile 64 x 256, BK=32, 4 waves each 64x64 (mi,nj in 0..3). T14 reg-prefetch.
// LDS kb-stride padded (65 / 257 rows) to derotate staging-write banks.
// ---------------------------------------------------------------------------
__global__ __launch_bounds__(256, 3) void gemm1_kernel(
        const float* __restrict__ x, const _Float16* __restrict__ w1t,
        const float* __restrict__ dis, _Float16* __restrict__ h1s, int M) {
    __shared__ _Float16 As[4 * 65 * 8];    // [kb][row pad65][8]
    __shared__ _Float16 Bs[4 * 257 * 8];   // [kb][col pad257][8]
    const int tid = threadIdx.x;
    const int brow = blockIdx.x * 64;
    const int w = tid >> 6, lane = tid & 63;
    const int wcol = w * 64;
    const int lrow = lane & 15, lkb = lane >> 4;

    // Staging geometry: A: thread -> (row = tid>>2, kb = tid&3) 8 floats.
    //                   B: 4 pieces p = tid + i*256 -> (col = p>>2, kb = p&3).
    const int arow = tid >> 2, akb = tid & 3;
    const int gr = brow + arow;
    const bool aval = gr < M;
    const float* xptr = x + (size_t)(aval ? gr : 0) * 512 + akb * 8;
    const _Float16* bbase = w1t + (size_t)arow * 512 + akb * 8;   // +i*64*512
    const int awr = (akb * 65 + arow) << 3;
    const int bwr0 = (akb * 257 + arow) << 3;                      // +i*64*8

    f32x4_t acc[4][4];
    #pragma unroll
    for (int mi = 0; mi < 4; ++mi)
        #pragma unroll
        for (int nj = 0; nj < 4; ++nj) acc[mi][nj] = (f32x4_t)0.f;

    float4 au = make_float4(0.f, 0.f, 0.f, 0.f);
    float4 av = make_float4(0.f, 0.f, 0.f, 0.f);
    half8_t bh0, bh1, bh2, bh3;

    // Prefetch tile 0.
    if (aval) { au = *(const float4*)(xptr); av = *(const float4*)(xptr + 4); }
    bh0 = *(const half8_t*)(bbase);
    bh1 = *(const half8_t*)(bbase + 64 * 512);
    bh2 = *(const half8_t*)(bbase + 128 * 512);
    bh3 = *(const half8_t*)(bbase + 192 * 512);

    for (int t = 0; t < 16; ++t) {
        __syncthreads();                       // prior compute done reading LDS
        half8_t ha;
        ha[0] = (_Float16)au.x; ha[1] = (_Float16)au.y;
        ha[2] = (_Float16)au.z; ha[3] = (_Float16)au.w;
        ha[4] = (_Float16)av.x; ha[5] = (_Float16)av.y;
        ha[6] = (_Float16)av.z; ha[7] = (_Float16)av.w;
        *(half8_t*)&As[awr] = ha;
        *(half8_t*)&Bs[bwr0] = bh0;
        *(half8_t*)&Bs[bwr0 + 64 * 8] = bh1;
        *(half8_t*)&Bs[bwr0 + 128 * 8] = bh2;
        *(half8_t*)&Bs[bwr0 + 192 * 8] = bh3;
        __syncthreads();                       // tile visible
        if (t < 15) {                          // issue next tile loads (hide under MFMA)
            int k0 = (t + 1) * 32;
            if (aval) {
                au = *(const float4*)(xptr + k0);
                av = *(const float4*)(xptr + k0 + 4);
            }
            bh0 = *(const half8_t*)(bbase + k0);
            bh1 = *(const half8_t*)(bbase + k0 + 64 * 512);
            bh2 = *(const half8_t*)(bbase + k0 + 128 * 512);
            bh3 = *(const half8_t*)(bbase + k0 + 192 * 512);
        }
        half8_t a[4], b[4];
        #pragma unroll
        for (int mi = 0; mi < 4; ++mi)
            a[mi] = *(const half8_t*)&As[(lkb * 65 + mi * 16 + lrow) << 3];
        #pragma unroll
        for (int nj = 0; nj < 4; ++nj)
            b[nj] = *(const half8_t*)&Bs[(lkb * 257 + wcol + nj * 16 + lrow) << 3];
        #pragma unroll
        for (int mi = 0; mi < 4; ++mi)
            #pragma unroll
            for (int nj = 0; nj < 4; ++nj)
                acc[mi][nj] = __builtin_amdgcn_mfma_f32_16x16x32_f16(a[mi], b[nj], acc[mi][nj], 0, 0, 0);
    }
    // Epilogue: C/D layout col=lane&15, row=(lane>>4)*4+r. Chunk-major store.
    #pragma unroll
    for (int mi = 0; mi < 4; ++mi) {
        #pragma unroll
        for (int r = 0; r < 4; ++r) {
            int grow = brow + mi * 16 + (lane >> 4) * 4 + r;
            if (grow >= M) continue;
            float s = dis[grow];
            #pragma unroll
            for (int nj = 0; nj < 4; ++nj) {
                int col = wcol + nj * 16 + lrow;
                h1s[((size_t)(col >> 5) * M + grow) * 32 + (col & 31)] =
                    (_Float16)(acc[mi][nj][r] * s);
            }
        }
    }
}

// ---------------------------------------------------------------------------
// GEMM2: h2[chunk][M][32] = fp16( (a1 @ W2) * dis[row] ), a1 chunk-major.
// Tile 64x64, 4 waves (wave = 16 rows x 64 cols), K=256, T14 reg-prefetch.
// ---------------------------------------------------------------------------
__global__ __launch_bounds__(256, 4) void gemm2_kernel(
        const _Float16* __restrict__ a1s, const _Float16* __restrict__ w2t,
        const float* __restrict__ dis, _Float16* __restrict__ h2s, int M) {
    __shared__ _Float16 As[4 * 65 * 8];
    __shared__ _Float16 Bs[4 * 65 * 8];
    const int tid = threadIdx.x;
    const int brow = blockIdx.x * 64;
    const int w = tid >> 6, lane = tid & 63;
    const int lrow = lane & 15, lkb = lane >> 4;

    const int arow = tid >> 2, akb = tid & 3;
    const int gr = brow + arow;
    const bool aval = gr < M;
    // a1s element for k-step t: ((t*M + gr)*32 + akb*8)  (chunk t = k0>>5)
    const _Float16* aptr = a1s + ((size_t)(aval ? gr : 0)) * 32 + akb * 8;
    const _Float16* bptr = w2t + (size_t)arow * 256 + akb * 8;    // arow = col 0..63
    const int awr = (akb * 65 + arow) << 3;

    f32x4_t acc[4];
    #pragma unroll
    for (int nj = 0; nj < 4; ++nj) acc[nj] = (f32x4_t)0.f;

    const half8_t zero8 = (half8_t)(_Float16)0.f;
    half8_t ah = zero8, bh;
    if (aval) ah = *(const half8_t*)(aptr);
    bh = *(const half8_t*)(bptr);

    for (int t = 0; t < 8; ++t) {
        __syncthreads();
        *(half8_t*)&As[awr] = ah;
        *(half8_t*)&Bs[awr] = bh;              // same (kb,idx) shape for B
        __syncthreads();
        if (t < 7) {
            if (aval) ah = *(const half8_t*)(aptr + (size_t)(t + 1) * M * 32);
            bh = *(const half8_t*)(bptr + (t + 1) * 32);
        }
        half8_t a = *(const half8_t*)&As[(lkb * 65 + w * 16 + lrow) << 3];
        half8_t b[4];
        #pragma unroll
        for (int nj = 0; nj < 4; ++nj)
            b[nj] = *(const half8_t*)&Bs[(lkb * 65 + nj * 16 + lrow) << 3];
        #pragma unroll
        for (int nj = 0; nj < 4; ++nj)
            acc[nj] = __builtin_amdgcn_mfma_f32_16x16x32_f16(a, b[nj], acc[nj], 0, 0, 0);
    }
    #pragma unroll
    for (int r = 0; r < 4; ++r) {
        int grow = brow + w * 16 + (lane >> 4) * 4 + r;
        if (grow >= M) continue;
        float s = dis[grow];
        #pragma unroll
        for (int nj = 0; nj < 4; ++nj) {
            int col = nj * 16 + lrow;
            h2s[((size_t)(col >> 5) * M + grow) * 32 + (col & 31)] =
                (_Float16)(acc[nj][r] * s);
        }
    }
}

__device__ __forceinline__ float4 up4(uint2 v) {
    __half2 h0 = *reinterpret_cast<__half2*>(&v.x);
    __half2 h1 = *reinterpret_cast<__half2*>(&v.y);
    float2 a = __half22float2(h0), b = __half22float2(h1);
    return make_float4(a.x, a.y, b.x, b.y);
}

// ---------------------------------------------------------------------------
// Chunked aggregation over [NCH][N][32] fp16, chunk pinned via blockIdx % NCH.
// One node per 8-lane group; register accumulate; no cross-lane reduce.
// ---------------------------------------------------------------------------
template<int NCH, int FP16OUT>
__global__ __launch_bounds__(256) void aggv_kernel(
        const _Float16* __restrict__ g, const int* __restrict__ offsets,
        const int* __restrict__ csr_src, const float* __restrict__ dis,
        const float* __restrict__ bias, void* __restrict__ out, int N) {
    const int chunk = blockIdx.x % NCH;
    const int node = (blockIdx.x / NCH) * 32 + (threadIdx.x >> 3);
    if (node >= N) return;
    const int cl = threadIdx.x & 7;
    const uint2* gc = (const uint2*)g + (size_t)chunk * N * 8;   // row = 8 uint2

    const int s0 = offsets[node], s1 = offsets[node + 1];
    const float s = dis[node];
    const float4 bb = *(const float4*)&bias[chunk * 32 + cl * 4];

    float4 accA = up4(gc[(size_t)node * 8 + cl]);   // self-loop
    float4 accB = make_float4(0.f, 0.f, 0.f, 0.f);
    int e = s0;
    for (; e + 2 <= s1; e += 2) {
        int sa = csr_src[e];
        int sb = csr_src[e + 1];
        float4 va = up4(gc[(size_t)sa * 8 + cl]);
        float4 vb = up4(gc[(size_t)sb * 8 + cl]);
        accA.x += va.x; accA.y += va.y; accA.z += va.z; accA.w += va.w;
        accB.x += vb.x; accB.y += vb.y; accB.z += vb.z; accB.w += vb.w;
    }
    if (e < s1) {
        int sa = csr_src[e];
        float4 va = up4(gc[(size_t)sa * 8 + cl]);
        accA.x += va.x; accA.y += va.y; accA.z += va.z; accA.w += va.w;
    }
    float4 o;
    o.x = fmaf(s, accA.x + accB.x, bb.x);
    o.y = fmaf(s, accA.y + accB.y, bb.y);
    o.z = fmaf(s, accA.z + accB.z, bb.z);
    o.w = fmaf(s, accA.w + accB.w, bb.w);
    if (FP16OUT) {
        o.x = fmaxf(o.x, 0.f); o.y = fmaxf(o.y, 0.f);
        o.z = fmaxf(o.z, 0.f); o.w = fmaxf(o.w, 0.f);
        __half2 p0 = __float22half2_rn(make_float2(o.x, o.y));
        __half2 p1 = __float22half2_rn(make_float2(o.z, o.w));
        uint2 pv;
        pv.x = *reinterpret_cast<unsigned*>(&p0);
        pv.y = *reinterpret_cast<unsigned*>(&p1);
        ((uint2*)out)[((size_t)chunk * N + node) * 8 + cl] = pv;
    } else {
        ((float4*)out)[(size_t)node * (NCH * 8) + chunk * 8 + cl] = o;
    }
}

extern "C" void kernel_launch(void* const* d_in, const int* in_sizes, int n_in,
                              void* d_out, int out_size, void* d_ws, size_t ws_size,
                              hipStream_t stream) {
    const float* x  = (const float*)d_in[0];
    const float* W1 = (const float*)d_in[1];
    const float* b1 = (const float*)d_in[2];
    const float* W2 = (const float*)d_in[3];
    const float* b2 = (const float*)d_in[4];
    const int* eidx = (const int*)d_in[5];

    const int HID = in_sizes[2];            // 256
    const int OUT = in_sizes[4];            // 64
    const int IN  = in_sizes[1] / HID;      // 512
    const int N   = in_sizes[0] / IN;       // 50000
    const int E   = in_sizes[5] / 2;        // 800000

    char* ws = (char*)d_ws;
    size_t off = 0;
    auto alloc = [&](size_t bytes) {
        off = (off + 255) & ~(size_t)255;
        char* p = ws + off;
        off += bytes;
        return p;
    };
    float* dis     = (float*)alloc((size_t)N * 4);
    int* counts    = (int*)alloc((size_t)N * 4);
    int* offsets   = (int*)alloc((size_t)(N + 1) * 4);
    int* cursor    = (int*)alloc((size_t)N * 4);
    int* partials  = (int*)alloc(4096);
    int* flag      = (int*)alloc(256);
    int* csr_src   = (int*)alloc((size_t)E * 4);
    _Float16* w1t  = (_Float16*)alloc((size_t)IN * HID * 2);
    _Float16* w2t  = (_Float16*)alloc((size_t)HID * OUT * 2);
    _Float16* h1s  = (_Float16*)alloc((size_t)N * HID * 2);   // [8][N][32]
    _Float16* a1s  = (_Float16*)alloc((size_t)N * HID * 2);   // [8][N][32]
    _Float16* h2s  = (_Float16*)alloc((size_t)N * OUT * 2);   // [2][N][32]

    const int nb = (N + 1023) / 1024;

    hipMemsetAsync(counts, 0, (size_t)N * 4, stream);
    detect_i64_kernel<<<1, 64, 0, stream>>>(eidx, flag);
    count_edges_kernel<<<(E + 255) / 256, 256, 0, stream>>>(eidx, flag, counts, E, N);
    scan1_kernel<<<nb, 1024, 0, stream>>>(counts, offsets, partials, N);
    scan2_kernel<<<1, 64, 0, stream>>>(partials, offsets, nb, N);
    scan3_kernel<<<nb, 1024, 0, stream>>>(counts, offsets, cursor, dis, partials, N);
    fill_csr_kernel<<<(E + 255) / 256, 256, 0, stream>>>(eidx, flag, cursor, csr_src, E, N);
    wt_kernel<<<(IN * HID + HID * OUT + 255) / 256, 256, 0, stream>>>(W1, W2, w1t, w2t);

    // Layer 1
    gemm1_kernel<<<(N + 63) / 64, 256, 0, stream>>>(x, w1t, dis, h1s, N);
    aggv_kernel<8, 1><<<((N + 31) / 32) * 8, 256, 0, stream>>>(h1s, offsets, csr_src, dis,
                                                               b1, a1s, N);
    // Layer 2
    gemm2_kernel<<<(N + 63) / 64, 256, 0, stream>>>(a1s, w2t, dis, h2s, N);
    aggv_kernel<2, 0><<<((N + 31) / 32) * 2, 256, 0, stream>>>(h2s, offsets, csr_src, dis,
                                                               b2, d_out, N);
}

// Round 7
// 224.195 us; speedup vs baseline: 1.5984x; 1.0887x over previous
//
#include <hip/hip_runtime.h>
#include <hip/hip_bf16.h>
#include <hip/hip_fp16.h>
#include <stdint.h>

typedef _Float16 half8_t __attribute__((ext_vector_type(8)));
typedef float f32x4_t __attribute__((ext_vector_type(4)));

// ---------------------------------------------------------------------------
// GCN 2-layer, fp16-MFMA path, chunk-major intermediates:
//   g = (x@W)*dis[row]  stored as [chunk][N][32] fp16 (chunk = 32 cols)
//   out[i] = dis[i]*(sum_e g[src]+g[i]) + b; aggregation chunk-pinned to XCD.
//   Agg: block stages its nodes' contiguous CSR slice in LDS; 8-lane groups
//   gather rows and accumulate via depth-2 fp16 pairwise tree + f32 master.
// ---------------------------------------------------------------------------

__global__ void detect_i64_kernel(const int* __restrict__ idx, int* __restrict__ flag) {
    int t = threadIdx.x;
    int v = idx[2 * t + 1];
    unsigned long long b = __ballot(v == 0);
    if (t == 0) *flag = (b == 0xFFFFFFFFFFFFFFFFULL) ? 1 : 0;
}

__device__ __forceinline__ int load_idx(const int* __restrict__ idx, long long pos, int is64) {
    return is64 ? idx[2 * pos] : idx[pos];
}

__global__ void count_edges_kernel(const int* __restrict__ idx, const int* __restrict__ flag,
                                   int* __restrict__ counts, int E, int N) {
    int e = blockIdx.x * blockDim.x + threadIdx.x;
    if (e >= E) return;
    int is64 = *flag;
    int d = load_idx(idx, (long long)E + e, is64);
    if ((unsigned)d < (unsigned)N) atomicAdd(&counts[d], 1);
}

__global__ __launch_bounds__(1024) void scan1_kernel(const int* __restrict__ counts,
                                                     int* __restrict__ offsets,
                                                     int* __restrict__ partials, int n) {
    __shared__ int buf[1024];
    int i = blockIdx.x * 1024 + threadIdx.x;
    int v = (i < n) ? counts[i] : 0;
    buf[threadIdx.x] = v;
    __syncthreads();
    #pragma unroll
    for (int off = 1; off < 1024; off <<= 1) {
        int t = (threadIdx.x >= (unsigned)off) ? buf[threadIdx.x - off] : 0;
        __syncthreads();
        buf[threadIdx.x] += t;
        __syncthreads();
    }
    if (i < n) offsets[i] = buf[threadIdx.x] - v;    // local exclusive
    if (threadIdx.x == 1023) partials[blockIdx.x] = buf[1023];
}

__global__ void scan2_kernel(int* __restrict__ partials, int* __restrict__ offsets,
                             int nb, int n) {
    if (nb <= 64) {
        int t = threadIdx.x;
        int orig = (t < nb) ? partials[t] : 0;
        int v = orig;
        #pragma unroll
        for (int off = 1; off < 64; off <<= 1) {
            int u = __shfl_up(v, off);
            if (t >= off) v += u;
        }
        if (t < nb) partials[t] = v - orig;
        if (t == nb - 1) offsets[n] = v;
    } else if (threadIdx.x == 0) {
        int s = 0;
        for (int b = 0; b < nb; ++b) { int t2 = partials[b]; partials[b] = s; s += t2; }
        offsets[n] = s;
    }
}

__global__ __launch_bounds__(1024) void scan3_kernel(const int* __restrict__ counts,
                                                     int* __restrict__ offsets,
                                                     int* __restrict__ cursor,
                                                     float* __restrict__ dis,
                                                     const int* __restrict__ partials, int n) {
    int i = blockIdx.x * 1024 + threadIdx.x;
    if (i >= n) return;
    int o = offsets[i] + partials[blockIdx.x];
    offsets[i] = o;
    cursor[i] = o;
    dis[i] = rsqrtf((float)(counts[i] + 1));
}

__global__ void fill_csr_kernel(const int* __restrict__ idx, const int* __restrict__ flag,
                                int* __restrict__ cursor, int* __restrict__ csr_src,
                                int E, int N) {
    int e = blockIdx.x * blockDim.x + threadIdx.x;
    if (e >= E) return;
    int is64 = *flag;
    int s = load_idx(idx, e, is64);
    int d = load_idx(idx, (long long)E + e, is64);
    if ((unsigned)d < (unsigned)N) {
        int pos = atomicAdd(&cursor[d], 1);
        csr_src[pos] = ((unsigned)s < (unsigned)N) ? s : 0;
    }
}

// Transpose-convert W1 [512][256] -> w1t fp16 [256][512], W2 [256][64] -> w2t fp16 [64][256].
__global__ void wt_kernel(const float* __restrict__ W1, const float* __restrict__ W2,
                          _Float16* __restrict__ w1t, _Float16* __restrict__ w2t) {
    int p = blockIdx.x * 256 + threadIdx.x;
    if (p < 512 * 256) {
        int k = p >> 8, n = p & 255;
        w1t[n * 512 + k] = (_Float16)W1[p];
    } else {
        int q = p - 512 * 256;
        if (q < 256 * 64) {
            int k = q >> 6, n = q & 63;
            w2t[n * 256 + k] = (_Float16)W2[q];
        }
    }
}

// ---------------------------------------------------------------------------
// GEMM1: h1[chunk][M][32] = fp16( (x[M,512] @ W1) * dis[row] ).
// Tile 64 x 256, BK=32, 4 waves each 64x64. T14 reg-prefetch, padded LDS.
// ---------------------------------------------------------------------------
__global__ __launch_bounds__(256, 3) void gemm1_kernel(
        const float* __restrict__ x, const _Float16* __restrict__ w1t,
        const float* __restrict__ dis, _Float16* __restrict__ h1s, int M) {
    __shared__ _Float16 As[4 * 65 * 8];    // [kb][row pad65][8]
    __shared__ _Float16 Bs[4 * 257 * 8];   // [kb][col pad257][8]
    const int tid = threadIdx.x;
    const int brow = blockIdx.x * 64;
    const int w = tid >> 6, lane = tid & 63;
    const int wcol = w * 64;
    const int lrow = lane & 15, lkb = lane >> 4;

    const int arow = tid >> 2, akb = tid & 3;
    const int gr = brow + arow;
    const bool aval = gr < M;
    const float* xptr = x + (size_t)(aval ? gr : 0) * 512 + akb * 8;
    const _Float16* bbase = w1t + (size_t)arow * 512 + akb * 8;
    const int awr = (akb * 65 + arow) << 3;
    const int bwr0 = (akb * 257 + arow) << 3;

    f32x4_t acc[4][4];
    #pragma unroll
    for (int mi = 0; mi < 4; ++mi)
        #pragma unroll
        for (int nj = 0; nj < 4; ++nj) acc[mi][nj] = (f32x4_t)0.f;

    float4 au = make_float4(0.f, 0.f, 0.f, 0.f);
    float4 av = make_float4(0.f, 0.f, 0.f, 0.f);
    half8_t bh0, bh1, bh2, bh3;

    if (aval) { au = *(const float4*)(xptr); av = *(const float4*)(xptr + 4); }
    bh0 = *(const half8_t*)(bbase);
    bh1 = *(const half8_t*)(bbase + 64 * 512);
    bh2 = *(const half8_t*)(bbase + 128 * 512);
    bh3 = *(const half8_t*)(bbase + 192 * 512);

    for (int t = 0; t < 16; ++t) {
        __syncthreads();
        half8_t ha;
        ha[0] = (_Float16)au.x; ha[1] = (_Float16)au.y;
        ha[2] = (_Float16)au.z; ha[3] = (_Float16)au.w;
        ha[4] = (_Float16)av.x; ha[5] = (_Float16)av.y;
        ha[6] = (_Float16)av.z; ha[7] = (_Float16)av.w;
        *(half8_t*)&As[awr] = ha;
        *(half8_t*)&Bs[bwr0] = bh0;
        *(half8_t*)&Bs[bwr0 + 64 * 8] = bh1;
        *(half8_t*)&Bs[bwr0 + 128 * 8] = bh2;
        *(half8_t*)&Bs[bwr0 + 192 * 8] = bh3;
        __syncthreads();
        if (t < 15) {
            int k0 = (t + 1) * 32;
            if (aval) {
                au = *(const float4*)(xptr + k0);
                av = *(const float4*)(xptr + k0 + 4);
            }
            bh0 = *(const half8_t*)(bbase + k0);
            bh1 = *(const half8_t*)(bbase + k0 + 64 * 512);
            bh2 = *(const half8_t*)(bbase + k0 + 128 * 512);
            bh3 = *(const half8_t*)(bbase + k0 + 192 * 512);
        }
        half8_t a[4], b[4];
        #pragma unroll
        for (int mi = 0; mi < 4; ++mi)
            a[mi] = *(const half8_t*)&As[(lkb * 65 + mi * 16 + lrow) << 3];
        #pragma unroll
        for (int nj = 0; nj < 4; ++nj)
            b[nj] = *(const half8_t*)&Bs[(lkb * 257 + wcol + nj * 16 + lrow) << 3];
        #pragma unroll
        for (int mi = 0; mi < 4; ++mi)
            #pragma unroll
            for (int nj = 0; nj < 4; ++nj)
                acc[mi][nj] = __builtin_amdgcn_mfma_f32_16x16x32_f16(a[mi], b[nj], acc[mi][nj], 0, 0, 0);
    }
    #pragma unroll
    for (int mi = 0; mi < 4; ++mi) {
        #pragma unroll
        for (int r = 0; r < 4; ++r) {
            int grow = brow + mi * 16 + (lane >> 4) * 4 + r;
            if (grow >= M) continue;
            float s = dis[grow];
            #pragma unroll
            for (int nj = 0; nj < 4; ++nj) {
                int col = wcol + nj * 16 + lrow;
                h1s[((size_t)(col >> 5) * M + grow) * 32 + (col & 31)] =
                    (_Float16)(acc[mi][nj][r] * s);
            }
        }
    }
}

// ---------------------------------------------------------------------------
// GEMM2: h2[chunk][M][32] = fp16( (a1 @ W2) * dis[row] ), a1 chunk-major.
// Tile 64x64, 4 waves, K=256, T14 reg-prefetch.
// ---------------------------------------------------------------------------
__global__ __launch_bounds__(256, 4) void gemm2_kernel(
        const _Float16* __restrict__ a1s, const _Float16* __restrict__ w2t,
        const float* __restrict__ dis, _Float16* __restrict__ h2s, int M) {
    __shared__ _Float16 As[4 * 65 * 8];
    __shared__ _Float16 Bs[4 * 65 * 8];
    const int tid = threadIdx.x;
    const int brow = blockIdx.x * 64;
    const int w = tid >> 6, lane = tid & 63;
    const int lrow = lane & 15, lkb = lane >> 4;

    const int arow = tid >> 2, akb = tid & 3;
    const int gr = brow + arow;
    const bool aval = gr < M;
    const _Float16* aptr = a1s + ((size_t)(aval ? gr : 0)) * 32 + akb * 8;
    const _Float16* bptr = w2t + (size_t)arow * 256 + akb * 8;
    const int awr = (akb * 65 + arow) << 3;

    f32x4_t acc[4];
    #pragma unroll
    for (int nj = 0; nj < 4; ++nj) acc[nj] = (f32x4_t)0.f;

    const half8_t zero8 = (half8_t)(_Float16)0.f;
    half8_t ah = zero8, bh;
    if (aval) ah = *(const half8_t*)(aptr);
    bh = *(const half8_t*)(bptr);

    for (int t = 0; t < 8; ++t) {
        __syncthreads();
        *(half8_t*)&As[awr] = ah;
        *(half8_t*)&Bs[awr] = bh;
        __syncthreads();
        if (t < 7) {
            if (aval) ah = *(const half8_t*)(aptr + (size_t)(t + 1) * M * 32);
            bh = *(const half8_t*)(bptr + (t + 1) * 32);
        }
        half8_t a = *(const half8_t*)&As[(lkb * 65 + w * 16 + lrow) << 3];
        half8_t b[4];
        #pragma unroll
        for (int nj = 0; nj < 4; ++nj)
            b[nj] = *(const half8_t*)&Bs[(lkb * 65 + nj * 16 + lrow) << 3];
        #pragma unroll
        for (int nj = 0; nj < 4; ++nj)
            acc[nj] = __builtin_amdgcn_mfma_f32_16x16x32_f16(a, b[nj], acc[nj], 0, 0, 0);
    }
    #pragma unroll
    for (int r = 0; r < 4; ++r) {
        int grow = brow + w * 16 + (lane >> 4) * 4 + r;
        if (grow >= M) continue;
        float s = dis[grow];
        #pragma unroll
        for (int nj = 0; nj < 4; ++nj) {
            int col = nj * 16 + lrow;
            h2s[((size_t)(col >> 5) * M + grow) * 32 + (col & 31)] =
                (_Float16)(acc[nj][r] * s);
        }
    }
}

__device__ __forceinline__ float4 up4(uint2 v) {
    __half2 h0 = *reinterpret_cast<__half2*>(&v.x);
    __half2 h1 = *reinterpret_cast<__half2*>(&v.y);
    float2 a = __half22float2(h0), b = __half22float2(h1);
    return make_float4(a.x, a.y, b.x, b.y);
}

__device__ __forceinline__ uint2 pk2(uint2 a, uint2 b) {
    __half2 ax = *reinterpret_cast<__half2*>(&a.x);
    __half2 ay = *reinterpret_cast<__half2*>(&a.y);
    __half2 bx = *reinterpret_cast<__half2*>(&b.x);
    __half2 by = *reinterpret_cast<__half2*>(&b.y);
    __half2 rx = __hadd2(ax, bx);
    __half2 ry = __hadd2(ay, by);
    uint2 r;
    r.x = *reinterpret_cast<unsigned*>(&rx);
    r.y = *reinterpret_cast<unsigned*>(&ry);
    return r;
}

// ---------------------------------------------------------------------------
// Chunked aggregation over [NCH][N][32] fp16, chunk pinned via blockIdx % NCH.
// Block = 32 nodes; stages the block's contiguous CSR slice into LDS.
// 8-lane group per node; depth-2 fp16 pairwise tree, f32 master accumulators.
// ---------------------------------------------------------------------------
template<int NCH, int FP16OUT>
__global__ __launch_bounds__(256) void aggv_kernel(
        const _Float16* __restrict__ g, const int* __restrict__ offsets,
        const int* __restrict__ csr_src, const float* __restrict__ dis,
        const float* __restrict__ bias, void* __restrict__ out, int N) {
    constexpr int CAP = 2048;
    __shared__ int lds_csr[CAP];
    const int chunk = blockIdx.x % NCH;
    const int nodeBase = (blockIdx.x / NCH) * 32;
    const int grp = threadIdx.x >> 3;
    const int cl = threadIdx.x & 7;
    const int node = nodeBase + grp;
    const bool active = node < N;
    const int nend = (nodeBase + 32 < N) ? nodeBase + 32 : N;
    const int blk0 = offsets[nodeBase];
    const int blk1 = offsets[nend];
    const uint2* gc = (const uint2*)g + (size_t)chunk * N * 8;   // row = 8 uint2

    int gs0 = 0, gs1 = 0;
    float s = 0.f;
    if (active) { gs0 = offsets[node]; gs1 = offsets[node + 1]; s = dis[node]; }

    float4 accA = make_float4(0.f, 0.f, 0.f, 0.f);
    float4 accB = make_float4(0.f, 0.f, 0.f, 0.f);
    if (active) accA = up4(gc[(size_t)node * 8 + cl]);   // self-loop term

    for (int base = blk0; base < blk1; base += CAP) {
        const int cnt = (blk1 - base < CAP) ? blk1 - base : CAP;
        __syncthreads();
        for (int i = threadIdx.x; i < cnt; i += 256)
            lds_csr[i] = csr_src[base + i];
        __syncthreads();
        int lo = (gs0 > base ? gs0 : base) - base;
        int hiv = (gs1 < base + cnt ? gs1 : base + cnt) - base;
        int e = lo;
        for (; e + 4 <= hiv; e += 4) {
            int s0 = lds_csr[e], s1 = lds_csr[e + 1];
            int s2 = lds_csr[e + 2], s3 = lds_csr[e + 3];
            uint2 v0 = gc[(size_t)s0 * 8 + cl];
            uint2 v1 = gc[(size_t)s1 * 8 + cl];
            uint2 v2 = gc[(size_t)s2 * 8 + cl];
            uint2 v3 = gc[(size_t)s3 * 8 + cl];
            uint2 q = pk2(pk2(v0, v1), pk2(v2, v3));   // depth-2 fp16 tree
            float4 f = up4(q);
            accA.x += f.x; accA.y += f.y; accA.z += f.z; accA.w += f.w;
        }
        for (; e < hiv; ++e) {
            int s0 = lds_csr[e];
            float4 f = up4(gc[(size_t)s0 * 8 + cl]);
            accB.x += f.x; accB.y += f.y; accB.z += f.z; accB.w += f.w;
        }
    }
    if (active) {
        float4 bb = *(const float4*)&bias[chunk * 32 + cl * 4];
        float4 o;
        o.x = fmaf(s, accA.x + accB.x, bb.x);
        o.y = fmaf(s, accA.y + accB.y, bb.y);
        o.z = fmaf(s, accA.z + accB.z, bb.z);
        o.w = fmaf(s, accA.w + accB.w, bb.w);
        if (FP16OUT) {
            o.x = fmaxf(o.x, 0.f); o.y = fmaxf(o.y, 0.f);
            o.z = fmaxf(o.z, 0.f); o.w = fmaxf(o.w, 0.f);
            __half2 p0 = __float22half2_rn(make_float2(o.x, o.y));
            __half2 p1 = __float22half2_rn(make_float2(o.z, o.w));
            uint2 pv;
            pv.x = *reinterpret_cast<unsigned*>(&p0);
            pv.y = *reinterpret_cast<unsigned*>(&p1);
            ((uint2*)out)[((size_t)chunk * N + node) * 8 + cl] = pv;
        } else {
            ((float4*)out)[(size_t)node * (NCH * 8) + chunk * 8 + cl] = o;
        }
    }
}

extern "C" void kernel_launch(void* const* d_in, const int* in_sizes, int n_in,
                              void* d_out, int out_size, void* d_ws, size_t ws_size,
                              hipStream_t stream) {
    const float* x  = (const float*)d_in[0];
    const float* W1 = (const float*)d_in[1];
    const float* b1 = (const float*)d_in[2];
    const float* W2 = (const float*)d_in[3];
    const float* b2 = (const float*)d_in[4];
    const int* eidx = (const int*)d_in[5];

    const int HID = in_sizes[2];            // 256
    const int OUT = in_sizes[4];            // 64
    const int IN  = in_sizes[1] / HID;      // 512
    const int N   = in_sizes[0] / IN;       // 50000
    const int E   = in_sizes[5] / 2;        // 800000

    char* ws = (char*)d_ws;
    size_t off = 0;
    auto alloc = [&](size_t bytes) {
        off = (off + 255) & ~(size_t)255;
        char* p = ws + off;
        off += bytes;
        return p;
    };
    float* dis     = (float*)alloc((size_t)N * 4);
    int* counts    = (int*)alloc((size_t)N * 4);
    int* offsets   = (int*)alloc((size_t)(N + 1) * 4);
    int* cursor    = (int*)alloc((size_t)N * 4);
    int* partials  = (int*)alloc(4096);
    int* flag      = (int*)alloc(256);
    int* csr_src   = (int*)alloc((size_t)E * 4);
    _Float16* w1t  = (_Float16*)alloc((size_t)IN * HID * 2);
    _Float16* w2t  = (_Float16*)alloc((size_t)HID * OUT * 2);
    _Float16* h1s  = (_Float16*)alloc((size_t)N * HID * 2);   // [8][N][32]
    _Float16* a1s  = (_Float16*)alloc((size_t)N * HID * 2);   // [8][N][32]
    _Float16* h2s  = (_Float16*)alloc((size_t)N * OUT * 2);   // [2][N][32]

    const int nb = (N + 1023) / 1024;

    hipMemsetAsync(counts, 0, (size_t)N * 4, stream);
    detect_i64_kernel<<<1, 64, 0, stream>>>(eidx, flag);
    count_edges_kernel<<<(E + 255) / 256, 256, 0, stream>>>(eidx, flag, counts, E, N);
    scan1_kernel<<<nb, 1024, 0, stream>>>(counts, offsets, partials, N);
    scan2_kernel<<<1, 64, 0, stream>>>(partials, offsets, nb, N);
    scan3_kernel<<<nb, 1024, 0, stream>>>(counts, offsets, cursor, dis, partials, N);
    fill_csr_kernel<<<(E + 255) / 256, 256, 0, stream>>>(eidx, flag, cursor, csr_src, E, N);
    wt_kernel<<<(IN * HID + HID * OUT + 255) / 256, 256, 0, stream>>>(W1, W2, w1t, w2t);

    // Layer 1
    gemm1_kernel<<<(N + 63) / 64, 256, 0, stream>>>(x, w1t, dis, h1s, N);
    aggv_kernel<8, 1><<<((N + 31) / 32) * 8, 256, 0, stream>>>(h1s, offsets, csr_src, dis,
                                                               b1, a1s, N);
    // Layer 2
    gemm2_kernel<<<(N + 63) / 64, 256, 0, stream>>>(a1s, w2t, dis, h2s, N);
    aggv_kernel<2, 0><<<((N + 31) / 32) * 2, 256, 0, stream>>>(h2s, offsets, csr_src, dis,
                                                               b2, d_out, N);
}